// Round 18
// baseline (230.047 us; speedup 1.0000x reference)
//
#include <hip/hip_runtime.h>

typedef unsigned short ushort;
typedef unsigned int uint;

typedef __attribute__((ext_vector_type(8))) short short8;     // bf16x8 MFMA frag
typedef __attribute__((ext_vector_type(8))) unsigned short ushort8;
typedef __attribute__((ext_vector_type(4))) unsigned short ushort4v;
typedef __attribute__((ext_vector_type(4))) float f32x4;
typedef __attribute__((ext_vector_type(4))) uint uint4v;

#define DEV static __device__ __forceinline__

DEV ushort f2b(float f){
  union { float f; uint u; } v; v.f = f;
  uint u = v.u;
  u += 0x7fffu + ((u >> 16) & 1u);   // round-to-nearest-even
  return (ushort)(u >> 16);
}
DEV float b2f(ushort h){
  union { uint u; float f; } v; v.u = ((uint)h) << 16;
  return v.f;
}
DEV uint cvt_pk_bf16(float lo, float hi){   // {bf16(lo), bf16(hi)} packed, RNE
  uint r;
  asm("v_cvt_pk_bf16_f32 %0, %1, %2" : "=v"(r) : "v"(lo), "v"(hi));
  return r;
}
DEV ushort f2b1(float f){ return (ushort)cvt_pk_bf16(f, f); }  // 1-inst bf16 convert
DEV float exp2v(float x){                   // 2^x, 1 inst
  float r;
  asm("v_exp_f32 %0, %1" : "=v"(r) : "v"(x));
  return r;
}
// exact-GELU via A&S 7.1.26 erf (|err| < 1.5e-7), exp2/rcp based
DEV float gelu_f(float x){
  float z = fabsf(x) * 0.70710678118654752f;
  float t = __builtin_amdgcn_rcpf(1.f + 0.3275911f * z);
  float poly = t * (0.254829592f + t * (-0.284496736f + t * (1.421413741f +
               t * (-1.453152027f + t * 1.061405429f))));
  float e = exp2v(-z * z * 1.44269504088896f);
  float erf_abs = 1.f - poly * e;
  float erf_s = copysignf(erf_abs, x);
  return 0.5f * x * (1.f + erf_s);
}

constexpr int Bc = 2, Tc = 2048, Dc = 1024, Hc = 16, DHc = 64, NBc = 32;
constexpr int Rc = Bc * Tc;   // 4096 rows
constexpr int D4c = 4 * Dc;   // 4096

// ---------------- ALL weight transposes + f32->bf16 in ONE launch ----------------
__global__ __launch_bounds__(256) void k_transcvt_all(
    const float* __restrict__ wq, const float* __restrict__ wk, const float* __restrict__ wv,
    const float* __restrict__ wo, const float* __restrict__ w1, const float* __restrict__ w2,
    ushort* __restrict__ wqT, ushort* __restrict__ wkT, ushort* __restrict__ wvT,
    ushort* __restrict__ woT, ushort* __restrict__ w1T, ushort* __restrict__ w2T){
  __shared__ float tile[32][33];
  const int bid = blockIdx.x;
  const float* in; ushort* out; int K, N, bx, by;
  if (bid < 4096){
    int seg = bid >> 10, loc = bid & 1023;
    in  = seg == 0 ? wq  : seg == 1 ? wk  : seg == 2 ? wv  : wo;
    out = seg == 0 ? wqT : seg == 1 ? wkT : seg == 2 ? wvT : woT;
    K = 1024; N = 1024; bx = loc & 31; by = loc >> 5;
  } else if (bid < 8192){
    int loc = bid - 4096;
    in = w1; out = w1T; K = 1024; N = 4096; bx = loc & 127; by = loc >> 7;
  } else {
    int loc = bid - 8192;
    in = w2; out = w2T; K = 4096; N = 1024; bx = loc & 31; by = loc >> 5;
  }
  int n0 = bx * 32, k0 = by * 32;
  int c = threadIdx.x & 31, r0 = threadIdx.x >> 5;
#pragma unroll
  for (int i = 0; i < 4; i++){
    int k = r0 + i * 8;
    tile[k][c] = in[(size_t)(k0 + k) * N + n0 + c];
  }
  __syncthreads();
#pragma unroll
  for (int i = 0; i < 4; i++){
    int n = r0 + i * 8;
    out[(size_t)(n0 + n) * K + k0 + c] = f2b(tile[c][n]);
  }
}

// ---------------- LayerNorm: f32 (R,D) -> bf16 (R,D) ----------------
__global__ __launch_bounds__(256) void k_ln(const float* __restrict__ x, const float* __restrict__ g,
                                            const float* __restrict__ bb, ushort* __restrict__ out){
  int row = blockIdx.x, tid = threadIdx.x;
  const f32x4* xr = (const f32x4*)(x + (size_t)row * Dc);
  f32x4 v = xr[tid];
  float s  = v.x + v.y + v.z + v.w;
  float ss = v.x*v.x + v.y*v.y + v.z*v.z + v.w*v.w;
#pragma unroll
  for (int off = 32; off > 0; off >>= 1){
    s  += __shfl_xor(s,  off, 64);
    ss += __shfl_xor(ss, off, 64);
  }
  __shared__ float red[2][4];
  int w = tid >> 6;
  if ((tid & 63) == 0){ red[0][w] = s; red[1][w] = ss; }
  __syncthreads();
  s  = red[0][0] + red[0][1] + red[0][2] + red[0][3];
  ss = red[1][0] + red[1][1] + red[1][2] + red[1][3];
  float mu  = s * (1.f / Dc);
  float var = ss * (1.f / Dc) - mu * mu;
  float rs  = rsqrtf(var + 1e-5f);
  f32x4 gv = ((const f32x4*)g)[tid];
  f32x4 bv = ((const f32x4*)bb)[tid];
  ushort4v o;
  o.x = f2b((v.x - mu) * rs * gv.x + bv.x);
  o.y = f2b((v.y - mu) * rs * gv.y + bv.y);
  o.z = f2b((v.z - mu) * rs * gv.z + bv.z);
  o.w = f2b((v.w - mu) * rs * gv.w + bv.w);
  ((ushort4v*)(out + (size_t)row * Dc))[tid] = o;
}

#define GLDS(src, dst) __builtin_amdgcn_global_load_lds( \
    (const __attribute__((address_space(1))) void*)(src), \
    (__attribute__((address_space(3))) void*)(dst), 16, 0, 0)

// ---------------- shared staging/core macros for the 128x128 QKV kernel ----------------
#define STAGE128(nb_, k0_) do { \
  _Pragma("unroll") \
  for (int i_ = 0; i_ < 4; i_++){ \
    int chunk_ = w * 4 + i_; \
    GLDS(A  + (size_t)(m0 + chunk_ * 8 + rloc) * K + (k0_) + gsrc * 8, &SM[nb_][0][chunk_ * 512]); \
    GLDS(Bt + (size_t)(n0 + chunk_ * 8 + rloc) * K + (k0_) + gsrc * 8, &SM[nb_][1][chunk_ * 512]); \
  } \
} while(0)

#define GEMM_CORE(cb_) do { \
  _Pragma("unroll") \
  for (int ks = 0; ks < 2; ks++){ \
    const int gs = (ks * 4 + lg) ^ l7; \
    short8 aF[4], bF[4]; \
    _Pragma("unroll") \
    for (int mi = 0; mi < 4; mi++) aF[mi] = *(const short8*)&SM[cb_][0][(arow + mi * 16) * 64 + gs * 8]; \
    _Pragma("unroll") \
    for (int ni = 0; ni < 4; ni++) bF[ni] = *(const short8*)&SM[cb_][1][(brow + ni * 16) * 64 + gs * 8]; \
    _Pragma("unroll") \
    for (int mi = 0; mi < 4; mi++) \
      _Pragma("unroll") \
      for (int ni = 0; ni < 4; ni++) \
        acc[mi][ni] = __builtin_amdgcn_mfma_f32_16x16x32_bf16(aF[mi], bF[ni], acc[mi][ni], 0, 0, 0); \
  } \
} while(0)

// ---------------- 128x64 bf16 MFMA GEMM staging/core (shared by n64 variants) ----------------
#define STAGE64(nb_, k0_) do { \
  _Pragma("unroll") \
  for (int i_ = 0; i_ < 4; i_++){ \
    int chunk_ = w * 4 + i_; \
    GLDS(A + (size_t)(m0 + chunk_ * 8 + rloc) * K + (k0_) + gsrc * 8, &SM[nb_][chunk_ * 512]); \
  } \
  _Pragma("unroll") \
  for (int j_ = 0; j_ < 2; j_++){ \
    int chunk_ = w * 2 + j_; \
    GLDS(Bt + (size_t)(n0 + chunk_ * 8 + rloc) * K + (k0_) + gsrc * 8, &SM[nb_][8192 + chunk_ * 512]); \
  } \
} while(0)

#define CORE64(cb_) do { \
  _Pragma("unroll") \
  for (int ks = 0; ks < 2; ks++){ \
    const int gs = (ks * 4 + lg) ^ l7; \
    short8 aF[2], bF[4]; \
    _Pragma("unroll") \
    for (int mi = 0; mi < 2; mi++) aF[mi] = *(const short8*)&SM[cb_][(arow + mi * 16) * 64 + gs * 8]; \
    _Pragma("unroll") \
    for (int ni = 0; ni < 4; ni++) bF[ni] = *(const short8*)&SM[cb_][8192 + (ni * 16 + la15) * 64 + gs * 8]; \
    _Pragma("unroll") \
    for (int mi = 0; mi < 2; mi++) \
      _Pragma("unroll") \
      for (int ni = 0; ni < 4; ni++) \
        acc[mi][ni] = __builtin_amdgcn_mfma_f32_16x16x32_bf16(aF[mi], bF[ni], acc[mi][ni], 0, 0, 0); \
  } \
} while(0)

// ---------------- n64, f32 out + residual (FFN2 / out-proj): 48KB LDS -> 3 blocks/CU ----------------
__global__ __launch_bounds__(256) void k_gemm_n64(const ushort* __restrict__ A, const ushort* __restrict__ Bt,
                                                  const float* __restrict__ bias, const float* __restrict__ resid,
                                                  float* __restrict__ Cout, int M, int N, int K){
  __shared__ ushort SM[2][12288];                 // [buf]: A [0,8192), B [8192,12288)
  const int tid = threadIdx.x;
  const int m0 = blockIdx.y * 128, n0 = blockIdx.x * 64;
  const int w = tid >> 6, lane = tid & 63;
  const int la15 = lane & 15, lg = lane >> 4, l7 = lane & 7;
  const int rloc = lane >> 3, gsrc = (lane & 7) ^ rloc;

  f32x4 acc[2][4];
#pragma unroll
  for (int i = 0; i < 2; i++)
#pragma unroll
    for (int j = 0; j < 4; j++) acc[i][j] = f32x4{0.f, 0.f, 0.f, 0.f};

  const int arow = w * 32 + la15;

  STAGE64(0, 0);
  __syncthreads();
  const int NT = K >> 6;
  for (int t = 0; t < NT; t++){
    const int cb = t & 1;
    if (t + 1 < NT) STAGE64(cb ^ 1, (t + 1) << 6);
    CORE64(cb);
    __syncthreads();
  }

#pragma unroll
  for (int mi = 0; mi < 2; mi++)
#pragma unroll
    for (int ni = 0; ni < 4; ni++){
      int cc = n0 + ni * 16 + la15;
      float bv = bias[cc];
      f32x4 a4 = acc[mi][ni];
#pragma unroll
      for (int r = 0; r < 4; r++){
        int rr = m0 + w * 32 + mi * 16 + lg * 4 + r;
        float v = a4[r] + bv + resid[(size_t)rr * N + cc];
        Cout[(size_t)rr * N + cc] = v;
      }
    }
}

// ---------------- n64, bf16 out + GELU (FFN1): 48KB LDS -> 3 blocks/CU ----------------
__global__ __launch_bounds__(256) void k_gemm_n64b(const ushort* __restrict__ A, const ushort* __restrict__ Bt,
                                                   const float* __restrict__ bias,
                                                   ushort* __restrict__ Cout, int M, int N, int K){
  __shared__ ushort SM[2][12288];
  const int tid = threadIdx.x;
  const int m0 = blockIdx.y * 128, n0 = blockIdx.x * 64;
  const int w = tid >> 6, lane = tid & 63;
  const int la15 = lane & 15, lg = lane >> 4, l7 = lane & 7;
  const int rloc = lane >> 3, gsrc = (lane & 7) ^ rloc;

  f32x4 acc[2][4];
#pragma unroll
  for (int i = 0; i < 2; i++)
#pragma unroll
    for (int j = 0; j < 4; j++) acc[i][j] = f32x4{0.f, 0.f, 0.f, 0.f};

  const int arow = w * 32 + la15;

  STAGE64(0, 0);
  __syncthreads();
  const int NT = K >> 6;
  for (int t = 0; t < NT; t++){
    const int cb = t & 1;
    if (t + 1 < NT) STAGE64(cb ^ 1, (t + 1) << 6);
    CORE64(cb);
    __syncthreads();
  }

  // epilogue: gelu -> bf16 through LDS bounce Cs[128][72] (pad 72 -> granule stride 9, bank-safe)
  ushort* Cs = &SM[0][0];                         // 9216 ushorts < 24576 available
#pragma unroll
  for (int mi = 0; mi < 2; mi++)
#pragma unroll
    for (int ni = 0; ni < 4; ni++){
      int ccl = ni * 16 + la15;
      float bv = bias[n0 + ccl];
      f32x4 a4 = acc[mi][ni];
#pragma unroll
      for (int r = 0; r < 4; r++){
        int rl = w * 32 + mi * 16 + lg * 4 + r;
        Cs[rl * 72 + ccl] = f2b1(gelu_f(a4[r] + bv));
      }
    }
  __syncthreads();
#pragma unroll
  for (int p = 0; p < 4; p++){
    int row = p * 32 + (tid >> 3);
    int col = (tid & 7) * 8;
    ushort8 vv = *(const ushort8*)&Cs[row * 72 + col];
    *(ushort8*)(Cout + (size_t)(m0 + row) * N + n0 + col) = vv;
  }
}

// ---------------- fused QKV GEMM (2-phase) + RoPE epilogue; V written transposed vT[bh][d][t] ----------------
__global__ __launch_bounds__(256) void k_gemm_qkv(const ushort* __restrict__ A, const ushort* __restrict__ Bt,
                                                  const float* __restrict__ bq_, const float* __restrict__ bk_,
                                                  const float* __restrict__ bv_, ushort* __restrict__ oq,
                                                  ushort* __restrict__ ok, ushort* __restrict__ ovt,
                                                  const float* __restrict__ cosa, const float* __restrict__ sina,
                                                  int K){
  __shared__ ushort SM[2][2][8192];
  const int tid = threadIdx.x;
  const int m0 = blockIdx.y * 128, n0 = blockIdx.x * 128;
  const int w = tid >> 6, lane = tid & 63;
  const int wr = w >> 1, wc = w & 1;
  const int la15 = lane & 15, lg = lane >> 4, l7 = lane & 7;
  const int rloc = lane >> 3, gsrc = (lane & 7) ^ rloc;

  f32x4 acc[4][4];
#pragma unroll
  for (int i = 0; i < 4; i++)
#pragma unroll
    for (int j = 0; j < 4; j++) acc[i][j] = f32x4{0.f, 0.f, 0.f, 0.f};

  const int arow = wr * 64 + la15;
  const int brow = wc * 64 + la15;

  STAGE128(0, 0);
  __syncthreads();
  const int NT = K >> 6;
  for (int t = 0; t < NT; t++){
    const int cb = t & 1;
    if (t + 1 < NT) STAGE128(cb ^ 1, (t + 1) << 6);
    GEMM_CORE(cb);
    __syncthreads();
  }
  __syncthreads();

  const int sel = n0 >> 10;                       // 0=Q, 1=K, 2=V (uniform per block)
  ushort* Cs = &SM[0][0][0];
  if (sel < 2){
    const float* bias = sel == 0 ? bq_ : bk_;
    ushort* o = sel == 0 ? oq : ok;
#pragma unroll
    for (int mi = 0; mi < 4; mi++)
#pragma unroll
      for (int ni = 0; ni < 4; ni++){
        int ccl = wc * 64 + ni * 16 + la15;
        float bv = bias[(n0 & 1023) + ccl];
        f32x4 a4 = acc[mi][ni];
#pragma unroll
        for (int r = 0; r < 4; r++){
          int rl = wr * 64 + mi * 16 + lg * 4 + r;
          Cs[rl * 136 + ccl] = f2b1(a4[r] + bv);
        }
      }
    __syncthreads();
    // store loop + fused RoPE (pairs are adjacent columns; nb0 is 4-aligned -> float4 cos/sin)
#pragma unroll
    for (int p = 0; p < 8; p++){
      int row = p * 16 + (tid >> 4);
      int col = (tid & 15) * 8;
      ushort8 vv = *(const ushort8*)&Cs[row * 136 + col];
      int rr = m0 + row;
      int bb2 = rr >> 11, tt2 = rr & 2047;
      int cg = (n0 & 1023) + col;                 // global col in [0,1024), mult of 8
      int hh2 = cg >> 6;
      int nb0 = (cg & 63) >> 1;                   // multiple of 4
      size_t ai = ((size_t)(bb2 * Hc + hh2) * Tc + tt2) * NBc + nb0;
      f32x4 cv = *(const f32x4*)(cosa + ai);
      f32x4 sv = *(const f32x4*)(sina + ai);
      ushort8 ov;
#pragma unroll
      for (int j2 = 0; j2 < 4; j2++){
        float x1 = b2f((ushort)vv[2 * j2]), x2 = b2f((ushort)vv[2 * j2 + 1]);
        uint pk = cvt_pk_bf16(x1 * cv[j2] - x2 * sv[j2], x1 * sv[j2] + x2 * cv[j2]);
        ov[2 * j2]     = (ushort)(pk & 0xffff);
        ov[2 * j2 + 1] = (ushort)(pk >> 16);
      }
      *(ushort8*)(o + (size_t)rr * Dc + cg) = ov;
    }
  } else {
    // V: transpose in LDS -> Cs[nloc 128][tloc 136], then 16B stores along t (no rope)
#pragma unroll
    for (int mi = 0; mi < 4; mi++)
#pragma unroll
      for (int ni = 0; ni < 4; ni++){
        int ccl = wc * 64 + ni * 16 + la15;       // nloc
        float bv = bv_[(n0 - 2048) + ccl];
        f32x4 a4 = acc[mi][ni];
#pragma unroll
        for (int r = 0; r < 4; r++){
          int rl = wr * 64 + mi * 16 + lg * 4 + r;  // tloc
          Cs[ccl * 136 + rl] = f2b1(a4[r] + bv);
        }
      }
    __syncthreads();
    const int bb = m0 >> 11, t0 = m0 & 2047;
#pragma unroll
    for (int p = 0; p < 8; p++){
      int nl = p * 16 + (tid >> 4);
      int tl = (tid & 15) * 8;
      ushort8 vv = *(const ushort8*)&Cs[nl * 136 + tl];
      int ng = (n0 - 2048) + nl;                  // 0..1023: hh*64 + d
      *(ushort8*)(ovt + ((size_t)(bb * 1024 + ng) << 11) + t0 + tl) = vv;
    }
  }
}

// ---------------- inv scale (exp2 domain): log2e / (8 * (1 + mean_nb sigma)), (B,H,T) ----------------
__global__ __launch_bounds__(256) void k_iscale(const float* __restrict__ sigma, float* __restrict__ isc){
  int idx = blockIdx.x * 256 + threadIdx.x;       // B*T*H = 65536, idx = (b*T+t)*H + h
  int hh = idx & 15;
  int t  = (idx >> 4) & 2047;
  int b  = idx >> 15;
  const f32x4* sp = (const f32x4*)(sigma + (size_t)idx * NBc);
  float s = 0.f;
#pragma unroll
  for (int i = 0; i < 8; i++){ f32x4 v = sp[i]; s += v.x + v.y + v.z + v.w; }
  isc[(b * Hc + hh) * Tc + t] = 1.44269504088896f / (8.f * (1.f + s * (1.f / NBc)));
}

// ---------------- MFMA causal flash attention: single-buffer GLDS-pipelined (round-9 proven) ----------------
__global__ __launch_bounds__(64) void k_attn_mfma(const ushort* __restrict__ qb, const ushort* __restrict__ kb,
                                                  const ushort* __restrict__ vtb, const float* __restrict__ isc,
                                                  ushort* __restrict__ ao){
  __shared__ ushort smem[8192];                   // 16KB: K [0,4096), V^T [4096,8192)
  const int bid = blockIdx.x;
  const int bh = bid & 31, b = bh >> 4, h = bh & 15;
  const int qt = 63 - (bid >> 5);                 // 0..63, big-first
  const int lane = threadIdx.x;
  const int la15 = lane & 15, lg = lane >> 4, l7 = lane & 7;
  const int q0w = qt * 32;

  short8 qf[2][2];
  float iscv[2];
#pragma unroll
  for (int sub = 0; sub < 2; sub++){
    int qg = q0w + sub * 16 + la15;
    size_t rb = (size_t)(b * Tc + qg) * Dc + h * DHc;
    qf[sub][0] = *(const short8*)(qb + rb + lg * 8);
    qf[sub][1] = *(const short8*)(qb + rb + 32 + lg * 8);
    iscv[sub] = isc[bh * Tc + qg];
  }

  f32x4 O[2][4];
#pragma unroll
  for (int sub = 0; sub < 2; sub++)
#pragma unroll
    for (int dt = 0; dt < 4; dt++) O[sub][dt] = f32x4{0.f, 0.f, 0.f, 0.f};
  float lacc[2] = {0.f, 0.f};

  const ushort* kbase  = kb + (size_t)b * Tc * Dc + h * DHc;
  const ushort* vtbase = vtb + (size_t)bh * DHc * Tc;
  const int ktmax = q0w + 31;

  const int Rl = lane >> 3, sl = lane & 7;
  const int gV = sl ^ (Rl & 7);

#define STAGE_KV(kt_) do { \
  _Pragma("unroll") \
  for (int i_ = 0; i_ < 8; i_++){ \
    int R_ = i_ * 8 + Rl; \
    int gk_ = sl ^ ((R_ & 3) ^ (((R_ >> 3) & 3) << 1)); \
    GLDS(kbase + (size_t)((kt_) + R_) * Dc + gk_ * 8, &smem[i_ * 512]); \
    GLDS(vtbase + (size_t)R_ * Tc + (kt_) + gV * 8, &smem[4096 + i_ * 512]); \
  } \
} while(0)

#define COMPUTE_T(kt_) do { \
  _Pragma("unroll") \
  for (int sub = 0; sub < 2; sub++){ \
    f32x4 s_[4]; \
    __builtin_amdgcn_s_setprio(1); \
    _Pragma("unroll") \
    for (int t_ = 0; t_ < 4; t_++){ \
      s_[t_] = f32x4{0.f, 0.f, 0.f, 0.f}; \
      s_[t_] = __builtin_amdgcn_mfma_f32_16x16x32_bf16(kf[t_][0], qf[sub][0], s_[t_], 0, 0, 0); \
      s_[t_] = __builtin_amdgcn_mfma_f32_16x16x32_bf16(kf[t_][1], qf[sub][1], s_[t_], 0, 0, 0); \
    } \
    __builtin_amdgcn_s_setprio(0); \
    const int qg_ = q0w + sub * 16 + la15; \
    const float sc_ = iscv[sub]; \
    const bool diag_ = ((kt_) + 63 > q0w + sub * 16); \
    uint up_[4][2]; \
    float lp_ = 0.f; \
    _Pragma("unroll") \
    for (int t_ = 0; t_ < 4; t_++){ \
      _Pragma("unroll") \
      for (int pr_ = 0; pr_ < 2; pr_++){ \
        float e0_ = exp2v(s_[t_][2 * pr_] * sc_); \
        float e1_ = exp2v(s_[t_][2 * pr_ + 1] * sc_); \
        if (diag_){ \
          int kp0_ = (kt_) + ((t_ >> 1) << 5) + lg * 8 + ((t_ & 1) << 2) + 2 * pr_; \
          if (kp0_ > qg_)     e0_ = 0.f; \
          if (kp0_ + 1 > qg_) e1_ = 0.f; \
        } \
        lp_ += e0_ + e1_; \
        up_[t_][pr_] = cvt_pk_bf16(e0_, e1_); \
      } \
    } \
    lacc[sub] += lp_; \
    __builtin_amdgcn_s_setprio(1); \
    _Pragma("unroll") \
    for (int kh_ = 0; kh_ < 2; kh_++){ \
      union { uint4v w; short8 s8; } pfr_; \
      pfr_.w[0] = up_[kh_ * 2][0];     pfr_.w[1] = up_[kh_ * 2][1]; \
      pfr_.w[2] = up_[kh_ * 2 + 1][0]; pfr_.w[3] = up_[kh_ * 2 + 1][1]; \
      _Pragma("unroll") \
      for (int dt_ = 0; dt_ < 4; dt_++) \
        O[sub][dt_] = __builtin_amdgcn_mfma_f32_16x16x32_bf16(vtf[dt_][kh_], pfr_.s8, O[sub][dt_], 0, 0, 0); \
    } \
    __builtin_amdgcn_s_setprio(0); \
  } \
} while(0)

  STAGE_KV(0);
  asm volatile("s_waitcnt vmcnt(0)" ::: "memory");
  __builtin_amdgcn_sched_barrier(0);

  for (int kt = 0;; kt += 64){
    short8 kf[4][2], vtf[4][2];
#pragma unroll
    for (int t_ = 0; t_ < 4; t_++){
      int r = ((t_ >> 1) << 5) + ((la15 >> 2) << 3) + ((t_ & 1) << 2) + (la15 & 3);
#pragma unroll
      for (int ds = 0; ds < 2; ds++){
        int g = (ds * 4 + lg) ^ ((la15 & 3) ^ ((la15 >> 2) << 1));
        kf[t_][ds] = *(const short8*)&smem[r * 64 + g * 8];
      }
    }
#pragma unroll
    for (int dt = 0; dt < 4; dt++){
      int d = dt * 16 + la15;
#pragma unroll
      for (int kh = 0; kh < 2; kh++){
        int g = (kh * 4 + lg) ^ (la15 & 7);
        vtf[dt][kh] = *(const short8*)&smem[4096 + d * 64 + g * 8];
      }
    }
    asm volatile("s_waitcnt lgkmcnt(0)" ::: "memory");
    __builtin_amdgcn_sched_barrier(0);
    STAGE_KV(kt + 64);
    COMPUTE_T(kt);
    if (kt + 64 > ktmax) break;
    asm volatile("s_waitcnt vmcnt(0)" ::: "memory");
    __builtin_amdgcn_sched_barrier(0);
  }
  asm volatile("s_waitcnt vmcnt(0)" ::: "memory");
  __builtin_amdgcn_sched_barrier(0);

  char* osb = (char*)smem;                        // 32 rows x 136 B
#pragma unroll
  for (int sub = 0; sub < 2; sub++){
    float lt = lacc[sub];
    lt += __shfl_xor(lt, 16, 64);
    lt += __shfl_xor(lt, 32, 64);
    float inv = 1.f / lt;
#pragma unroll
    for (int dt = 0; dt < 4; dt++)
#pragma unroll
      for (int pr = 0; pr < 2; pr++){
        uint u = cvt_pk_bf16(O[sub][dt][2 * pr] * inv, O[sub][dt][2 * pr + 1] * inv);
        *(uint*)(osb + (sub * 16 + la15) * 136 + (dt * 16 + lg * 4 + pr * 2) * 2) = u;
      }
  }
#pragma unroll
  for (int it = 0; it < 4; it++){
    int ql = it * 8 + (lane >> 3);
    ushort8 v = *(const ushort8*)(osb + ql * 136 + l7 * 16);
    *(ushort8*)(ao + (size_t)(b * Tc + q0w + ql) * Dc + h * DHc + l7 * 8) = v;
  }
}

// ---------------- host ----------------
extern "C" void kernel_launch(void* const* d_in, const int* in_sizes, int n_in,
                              void* d_out, int out_size, void* d_ws, size_t ws_size,
                              hipStream_t stream){
  (void)in_sizes; (void)n_in; (void)out_size; (void)ws_size;
  const float* x    = (const float*)d_in[0];
  const float* cosa = (const float*)d_in[1];
  const float* sina = (const float*)d_in[2];
  const float* sigma= (const float*)d_in[3];
  // d_in[4] = causal_mask (unused; causality handled analytically)
  const float* ln1g = (const float*)d_in[5];
  const float* ln1b = (const float*)d_in[6];
  const float* wq   = (const float*)d_in[7];
  const float* bq   = (const float*)d_in[8];
  const float* wk   = (const float*)d_in[9];
  const float* bk   = (const float*)d_in[10];
  const float* wv   = (const float*)d_in[11];
  const float* bv   = (const float*)d_in[12];
  const float* wo   = (const float*)d_in[13];
  const float* bo   = (const float*)d_in[14];
  const float* ln2g = (const float*)d_in[15];
  const float* ln2b = (const float*)d_in[16];
  const float* w1   = (const float*)d_in[17];
  const float* b1   = (const float*)d_in[18];
  const float* w2   = (const float*)d_in[19];
  const float* b2   = (const float*)d_in[20];
  float* out = (float*)d_out;

  char* ws = (char*)d_ws;
  constexpr size_t MB = 1024 * 1024;
  ushort* wqT  = (ushort*)(ws +  0 * MB);  // 2MB each; wqT/wkT/wvT contiguous = 3072x1024
  ushort* wkT  = (ushort*)(ws +  2 * MB);
  ushort* wvT  = (ushort*)(ws +  4 * MB);
  ushort* woT  = (ushort*)(ws +  6 * MB);
  ushort* w1T  = (ushort*)(ws +  8 * MB);  // 8MB  (4D x D)
  ushort* w2T  = (ushort*)(ws + 16 * MB);  // 8MB  (D x 4D)
  ushort* hb   = (ushort*)(ws + 24 * MB);  // 8MB  h (bf16); reused for h2 after attention
  ushort* qbuf = (ushort*)(ws + 32 * MB);  // 8MB; [32..64)MB reused as gelu-out (32MB) in FFN
  ushort* kbuf = (ushort*)(ws + 40 * MB);
  ushort* vtb  = (ushort*)(ws + 48 * MB);  // 8MB  V^T [bh][64 d][2048 t]
  ushort* aob  = (ushort*)(ws + 56 * MB);
  float*  x2   = (float*)(ws + 64 * MB);   // 16MB
  float*  iscp = (float*)(ws + 80 * MB);   // 256KB
  ushort* g1b  = qbuf;                     // 32MB alias over qbuf/kbuf/vtb/aob (dead by then)

  // 1. ALL weight transposes in one launch
  k_transcvt_all<<<12288, 256, 0, stream>>>(wq, wk, wv, wo, w1, w2, wqT, wkT, wvT, woT, w1T, w2T);
  // 2. LN1
  k_ln<<<Rc, 256, 0, stream>>>(x, ln1g, ln1b, hb);
  // 3. fused QKV projection + RoPE epilogue (Q,K row-major roped; V transposed)
  k_gemm_qkv<<<dim3(3 * Dc / 128, Rc / 128), 256, 0, stream>>>(hb, wqT, bq, bk, bv, qbuf, kbuf, vtb,
                                                               cosa, sina, Dc);
  // 4. temperature -> inv scale (exp2 domain)
  k_iscale<<<(Bc * Tc * Hc) / 256, 256, 0, stream>>>(sigma, iscp);
  // 5. causal attention (MFMA flash, single-buffer GLDS-pipelined)
  k_attn_mfma<<<dim3(2048), 64, 0, stream>>>(qbuf, kbuf, vtb, iscp, aob);
  // 6. out-proj + residual (f32 out, n64 tile -> 3 blocks/CU)
  k_gemm_n64<<<dim3(Dc / 64, Rc / 128), 256, 0, stream>>>(aob, woT, bo, x, x2, Rc, Dc, Dc);
  // 7. LN2
  k_ln<<<Rc, 256, 0, stream>>>(x2, ln2g, ln2b, hb);
  // 8. FFN1 + exact GELU (bf16 out, n64 tile -> 3 blocks/CU)
  k_gemm_n64b<<<dim3(D4c / 64, Rc / 128), 256, 0, stream>>>(hb, w1T, b1, g1b, Rc, D4c, Dc);
  // 9. FFN2 + residual -> final output (f32, n64 tile -> 3 blocks/CU)
  k_gemm_n64<<<dim3(Dc / 64, Rc / 128), 256, 0, stream>>>(g1b, w2T, b2, x2, out, Rc, Dc, D4c);
}

// Round 19
// 225.916 us; speedup vs baseline: 1.0183x; 1.0183x over previous
//
#include <hip/hip_runtime.h>

typedef unsigned short ushort;
typedef unsigned int uint;

typedef __attribute__((ext_vector_type(8))) short short8;     // bf16x8 MFMA frag
typedef __attribute__((ext_vector_type(8))) unsigned short ushort8;
typedef __attribute__((ext_vector_type(4))) unsigned short ushort4v;
typedef __attribute__((ext_vector_type(4))) float f32x4;
typedef __attribute__((ext_vector_type(4))) uint uint4v;

#define DEV static __device__ __forceinline__

DEV ushort f2b(float f){
  union { float f; uint u; } v; v.f = f;
  uint u = v.u;
  u += 0x7fffu + ((u >> 16) & 1u);   // round-to-nearest-even
  return (ushort)(u >> 16);
}
DEV float b2f(ushort h){
  union { uint u; float f; } v; v.u = ((uint)h) << 16;
  return v.f;
}
DEV uint cvt_pk_bf16(float lo, float hi){   // {bf16(lo), bf16(hi)} packed, RNE
  uint r;
  asm("v_cvt_pk_bf16_f32 %0, %1, %2" : "=v"(r) : "v"(lo), "v"(hi));
  return r;
}
DEV ushort f2b1(float f){ return (ushort)cvt_pk_bf16(f, f); }  // 1-inst bf16 convert
DEV float exp2v(float x){                   // 2^x, 1 inst
  float r;
  asm("v_exp_f32 %0, %1" : "=v"(r) : "v"(x));
  return r;
}
// exact-GELU via A&S 7.1.26 erf (|err| < 1.5e-7), exp2/rcp based
DEV float gelu_f(float x){
  float z = fabsf(x) * 0.70710678118654752f;
  float t = __builtin_amdgcn_rcpf(1.f + 0.3275911f * z);
  float poly = t * (0.254829592f + t * (-0.284496736f + t * (1.421413741f +
               t * (-1.453152027f + t * 1.061405429f))));
  float e = exp2v(-z * z * 1.44269504088896f);
  float erf_abs = 1.f - poly * e;
  float erf_s = copysignf(erf_abs, x);
  return 0.5f * x * (1.f + erf_s);
}

constexpr int Bc = 2, Tc = 2048, Dc = 1024, Hc = 16, DHc = 64, NBc = 32;
constexpr int Rc = Bc * Tc;   // 4096 rows
constexpr int D4c = 4 * Dc;   // 4096

// ---------------- ALL weight transposes + f32->bf16 in ONE launch ----------------
__global__ __launch_bounds__(256) void k_transcvt_all(
    const float* __restrict__ wq, const float* __restrict__ wk, const float* __restrict__ wv,
    const float* __restrict__ wo, const float* __restrict__ w1, const float* __restrict__ w2,
    ushort* __restrict__ wqT, ushort* __restrict__ wkT, ushort* __restrict__ wvT,
    ushort* __restrict__ woT, ushort* __restrict__ w1T, ushort* __restrict__ w2T){
  __shared__ float tile[32][33];
  const int bid = blockIdx.x;
  const float* in; ushort* out; int K, N, bx, by;
  if (bid < 4096){
    int seg = bid >> 10, loc = bid & 1023;
    in  = seg == 0 ? wq  : seg == 1 ? wk  : seg == 2 ? wv  : wo;
    out = seg == 0 ? wqT : seg == 1 ? wkT : seg == 2 ? wvT : woT;
    K = 1024; N = 1024; bx = loc & 31; by = loc >> 5;
  } else if (bid < 8192){
    int loc = bid - 4096;
    in = w1; out = w1T; K = 1024; N = 4096; bx = loc & 127; by = loc >> 7;
  } else {
    int loc = bid - 8192;
    in = w2; out = w2T; K = 4096; N = 1024; bx = loc & 31; by = loc >> 5;
  }
  int n0 = bx * 32, k0 = by * 32;
  int c = threadIdx.x & 31, r0 = threadIdx.x >> 5;
#pragma unroll
  for (int i = 0; i < 4; i++){
    int k = r0 + i * 8;
    tile[k][c] = in[(size_t)(k0 + k) * N + n0 + c];
  }
  __syncthreads();
#pragma unroll
  for (int i = 0; i < 4; i++){
    int n = r0 + i * 8;
    out[(size_t)(n0 + n) * K + k0 + c] = f2b(tile[c][n]);
  }
}

// ---------------- LayerNorm: f32 (R,D) -> bf16 (R,D) ----------------
__global__ __launch_bounds__(256) void k_ln(const float* __restrict__ x, const float* __restrict__ g,
                                            const float* __restrict__ bb, ushort* __restrict__ out){
  int row = blockIdx.x, tid = threadIdx.x;
  const f32x4* xr = (const f32x4*)(x + (size_t)row * Dc);
  f32x4 v = xr[tid];
  float s  = v.x + v.y + v.z + v.w;
  float ss = v.x*v.x + v.y*v.y + v.z*v.z + v.w*v.w;
#pragma unroll
  for (int off = 32; off > 0; off >>= 1){
    s  += __shfl_xor(s,  off, 64);
    ss += __shfl_xor(ss, off, 64);
  }
  __shared__ float red[2][4];
  int w = tid >> 6;
  if ((tid & 63) == 0){ red[0][w] = s; red[1][w] = ss; }
  __syncthreads();
  s  = red[0][0] + red[0][1] + red[0][2] + red[0][3];
  ss = red[1][0] + red[1][1] + red[1][2] + red[1][3];
  float mu  = s * (1.f / Dc);
  float var = ss * (1.f / Dc) - mu * mu;
  float rs  = rsqrtf(var + 1e-5f);
  f32x4 gv = ((const f32x4*)g)[tid];
  f32x4 bv = ((const f32x4*)bb)[tid];
  ushort4v o;
  o.x = f2b((v.x - mu) * rs * gv.x + bv.x);
  o.y = f2b((v.y - mu) * rs * gv.y + bv.y);
  o.z = f2b((v.z - mu) * rs * gv.z + bv.z);
  o.w = f2b((v.w - mu) * rs * gv.w + bv.w);
  ((ushort4v*)(out + (size_t)row * Dc))[tid] = o;
}

#define GLDS(src, dst) __builtin_amdgcn_global_load_lds( \
    (const __attribute__((address_space(1))) void*)(src), \
    (__attribute__((address_space(3))) void*)(dst), 16, 0, 0)

// ---------------- 128x64 bf16 MFMA GEMM staging/core (shared by n64 variants) ----------------
#define STAGE64(nb_, k0_) do { \
  _Pragma("unroll") \
  for (int i_ = 0; i_ < 4; i_++){ \
    int chunk_ = w * 4 + i_; \
    GLDS(A + (size_t)(m0 + chunk_ * 8 + rloc) * K + (k0_) + gsrc * 8, &SM[nb_][chunk_ * 512]); \
  } \
  _Pragma("unroll") \
  for (int j_ = 0; j_ < 2; j_++){ \
    int chunk_ = w * 2 + j_; \
    GLDS(Bt + (size_t)(n0 + chunk_ * 8 + rloc) * K + (k0_) + gsrc * 8, &SM[nb_][8192 + chunk_ * 512]); \
  } \
} while(0)

#define CORE64(cb_) do { \
  _Pragma("unroll") \
  for (int ks = 0; ks < 2; ks++){ \
    const int gs = (ks * 4 + lg) ^ l7; \
    short8 aF[2], bF[4]; \
    _Pragma("unroll") \
    for (int mi = 0; mi < 2; mi++) aF[mi] = *(const short8*)&SM[cb_][(arow + mi * 16) * 64 + gs * 8]; \
    _Pragma("unroll") \
    for (int ni = 0; ni < 4; ni++) bF[ni] = *(const short8*)&SM[cb_][8192 + (ni * 16 + la15) * 64 + gs * 8]; \
    _Pragma("unroll") \
    for (int mi = 0; mi < 2; mi++) \
      _Pragma("unroll") \
      for (int ni = 0; ni < 4; ni++) \
        acc[mi][ni] = __builtin_amdgcn_mfma_f32_16x16x32_bf16(aF[mi], bF[ni], acc[mi][ni], 0, 0, 0); \
  } \
} while(0)

#define N64_LOOP() do { \
  STAGE64(0, 0); \
  __syncthreads(); \
  const int NT_ = K >> 6; \
  for (int t = 0; t < NT_; t++){ \
    const int cb = t & 1; \
    if (t + 1 < NT_) STAGE64(cb ^ 1, (t + 1) << 6); \
    CORE64(cb); \
    __syncthreads(); \
  } \
} while(0)

// ---------------- n64, f32 out + residual (FFN2 / out-proj): 48KB LDS -> 3 blocks/CU ----------------
__global__ __launch_bounds__(256) void k_gemm_n64(const ushort* __restrict__ A, const ushort* __restrict__ Bt,
                                                  const float* __restrict__ bias, const float* __restrict__ resid,
                                                  float* __restrict__ Cout, int M, int N, int K){
  __shared__ ushort SM[2][12288];                 // [buf]: A [0,8192), B [8192,12288)
  const int tid = threadIdx.x;
  const int m0 = blockIdx.y * 128, n0 = blockIdx.x * 64;
  const int w = tid >> 6, lane = tid & 63;
  const int la15 = lane & 15, lg = lane >> 4, l7 = lane & 7;
  const int rloc = lane >> 3, gsrc = (lane & 7) ^ rloc;

  f32x4 acc[2][4];
#pragma unroll
  for (int i = 0; i < 2; i++)
#pragma unroll
    for (int j = 0; j < 4; j++) acc[i][j] = f32x4{0.f, 0.f, 0.f, 0.f};

  const int arow = w * 32 + la15;

  N64_LOOP();

#pragma unroll
  for (int mi = 0; mi < 2; mi++)
#pragma unroll
    for (int ni = 0; ni < 4; ni++){
      int cc = n0 + ni * 16 + la15;
      float bv = bias[cc];
      f32x4 a4 = acc[mi][ni];
#pragma unroll
      for (int r = 0; r < 4; r++){
        int rr = m0 + w * 32 + mi * 16 + lg * 4 + r;
        float v = a4[r] + bv + resid[(size_t)rr * N + cc];
        Cout[(size_t)rr * N + cc] = v;
      }
    }
}

// ---------------- n64, bf16 out + GELU (FFN1): 48KB LDS -> 3 blocks/CU ----------------
__global__ __launch_bounds__(256) void k_gemm_n64b(const ushort* __restrict__ A, const ushort* __restrict__ Bt,
                                                   const float* __restrict__ bias,
                                                   ushort* __restrict__ Cout, int M, int N, int K){
  __shared__ ushort SM[2][12288];
  const int tid = threadIdx.x;
  const int m0 = blockIdx.y * 128, n0 = blockIdx.x * 64;
  const int w = tid >> 6, lane = tid & 63;
  const int la15 = lane & 15, lg = lane >> 4, l7 = lane & 7;
  const int rloc = lane >> 3, gsrc = (lane & 7) ^ rloc;

  f32x4 acc[2][4];
#pragma unroll
  for (int i = 0; i < 2; i++)
#pragma unroll
    for (int j = 0; j < 4; j++) acc[i][j] = f32x4{0.f, 0.f, 0.f, 0.f};

  const int arow = w * 32 + la15;

  N64_LOOP();

  // epilogue: gelu -> bf16 through LDS bounce Cs[128][72]
  ushort* Cs = &SM[0][0];
#pragma unroll
  for (int mi = 0; mi < 2; mi++)
#pragma unroll
    for (int ni = 0; ni < 4; ni++){
      int ccl = ni * 16 + la15;
      float bv = bias[n0 + ccl];
      f32x4 a4 = acc[mi][ni];
#pragma unroll
      for (int r = 0; r < 4; r++){
        int rl = w * 32 + mi * 16 + lg * 4 + r;
        Cs[rl * 72 + ccl] = f2b1(gelu_f(a4[r] + bv));
      }
    }
  __syncthreads();
#pragma unroll
  for (int p = 0; p < 4; p++){
    int row = p * 32 + (tid >> 3);
    int col = (tid & 7) * 8;
    ushort8 vv = *(const ushort8*)&Cs[row * 72 + col];
    *(ushort8*)(Cout + (size_t)(m0 + row) * N + n0 + col) = vv;
  }
}

// ---------------- n64 fused QKV GEMM + RoPE epilogue; V written transposed vT[bh][d][t] ----------------
// Grid (3072/64=48) x (4096/128=32) = 1536 blocks = 6/CU dispatched, 3/CU resident (48KB LDS).
__global__ __launch_bounds__(256) void k_gemm_qkv64(const ushort* __restrict__ A, const ushort* __restrict__ Bt,
                                                    const float* __restrict__ bq_, const float* __restrict__ bk_,
                                                    const float* __restrict__ bv_, ushort* __restrict__ oq,
                                                    ushort* __restrict__ ok, ushort* __restrict__ ovt,
                                                    const float* __restrict__ cosa, const float* __restrict__ sina,
                                                    int K){
  __shared__ ushort SM[2][12288];
  const int tid = threadIdx.x;
  const int m0 = blockIdx.y * 128, n0 = blockIdx.x * 64;
  const int w = tid >> 6, lane = tid & 63;
  const int la15 = lane & 15, lg = lane >> 4, l7 = lane & 7;
  const int rloc = lane >> 3, gsrc = (lane & 7) ^ rloc;

  f32x4 acc[2][4];
#pragma unroll
  for (int i = 0; i < 2; i++)
#pragma unroll
    for (int j = 0; j < 4; j++) acc[i][j] = f32x4{0.f, 0.f, 0.f, 0.f};

  const int arow = w * 32 + la15;

  N64_LOOP();

  const int sel = n0 >> 10;                       // 0=Q, 1=K, 2=V (uniform per block)
  ushort* Cs = &SM[0][0];
  if (sel < 2){
    const float* bias = sel == 0 ? bq_ : bk_;
    ushort* o = sel == 0 ? oq : ok;
    // bounce Cs[128][72] bf16 (pre-rope values)
#pragma unroll
    for (int mi = 0; mi < 2; mi++)
#pragma unroll
      for (int ni = 0; ni < 4; ni++){
        int ccl = ni * 16 + la15;
        float bv = bias[(n0 & 1023) + ccl];
        f32x4 a4 = acc[mi][ni];
#pragma unroll
        for (int r = 0; r < 4; r++){
          int rl = w * 32 + mi * 16 + lg * 4 + r;
          Cs[rl * 72 + ccl] = f2b1(a4[r] + bv);
        }
      }
    __syncthreads();
    // coalesced store + fused RoPE (pairs adjacent; cg 8-aligned -> float4 cos/sin)
#pragma unroll
    for (int p = 0; p < 4; p++){
      int row = p * 32 + (tid >> 3);
      int col = (tid & 7) * 8;
      ushort8 vv = *(const ushort8*)&Cs[row * 72 + col];
      int rr = m0 + row;
      int bb2 = rr >> 11, tt2 = rr & 2047;
      int cg = (n0 & 1023) + col;                 // global col in [0,1024), mult of 8
      int hh2 = cg >> 6;
      int nb0 = (cg & 63) >> 1;                   // multiple of 4
      size_t ai = ((size_t)(bb2 * Hc + hh2) * Tc + tt2) * NBc + nb0;
      f32x4 cv = *(const f32x4*)(cosa + ai);
      f32x4 sv = *(const f32x4*)(sina + ai);
      ushort8 ov;
#pragma unroll
      for (int j2 = 0; j2 < 4; j2++){
        float x1 = b2f((ushort)vv[2 * j2]), x2 = b2f((ushort)vv[2 * j2 + 1]);
        uint pk = cvt_pk_bf16(x1 * cv[j2] - x2 * sv[j2], x1 * sv[j2] + x2 * cv[j2]);
        ov[2 * j2]     = (ushort)(pk & 0xffff);
        ov[2 * j2 + 1] = (ushort)(pk >> 16);
      }
      *(ushort8*)(o + (size_t)rr * Dc + cg) = ov;
    }
  } else {
    // V: transpose bounce Cs[nloc 64][tloc 136], 16B stores along t (no rope)
#pragma unroll
    for (int mi = 0; mi < 2; mi++)
#pragma unroll
      for (int ni = 0; ni < 4; ni++){
        int ccl = ni * 16 + la15;                 // nloc 0..63
        float bv = bv_[(n0 - 2048) + ccl];
        f32x4 a4 = acc[mi][ni];
#pragma unroll
        for (int r = 0; r < 4; r++){
          int rl = w * 32 + mi * 16 + lg * 4 + r; // tloc 0..127
          Cs[ccl * 136 + rl] = f2b1(a4[r] + bv);
        }
      }
    __syncthreads();
    const int bb = m0 >> 11, t0 = m0 & 2047;
#pragma unroll
    for (int p = 0; p < 4; p++){
      int nl = p * 16 + (tid >> 4);               // 0..63
      int tl = (tid & 15) * 8;                    // 0..120
      ushort8 vv = *(const ushort8*)&Cs[nl * 136 + tl];
      int ng = (n0 - 2048) + nl;                  // hh*64 + d
      *(ushort8*)(ovt + ((size_t)(bb * 1024 + ng) << 11) + t0 + tl) = vv;
    }
  }
}

// ---------------- inv scale (exp2 domain): log2e / (8 * (1 + mean_nb sigma)), (B,H,T) ----------------
__global__ __launch_bounds__(256) void k_iscale(const float* __restrict__ sigma, float* __restrict__ isc){
  int idx = blockIdx.x * 256 + threadIdx.x;       // B*T*H = 65536, idx = (b*T+t)*H + h
  int hh = idx & 15;
  int t  = (idx >> 4) & 2047;
  int b  = idx >> 15;
  const f32x4* sp = (const f32x4*)(sigma + (size_t)idx * NBc);
  float s = 0.f;
#pragma unroll
  for (int i = 0; i < 8; i++){ f32x4 v = sp[i]; s += v.x + v.y + v.z + v.w; }
  isc[(b * Hc + hh) * Tc + t] = 1.44269504088896f / (8.f * (1.f + s * (1.f / NBc)));
}

// ---------------- MFMA causal flash attention: single-buffer GLDS-pipelined (round-9 proven) ----------------
__global__ __launch_bounds__(64) void k_attn_mfma(const ushort* __restrict__ qb, const ushort* __restrict__ kb,
                                                  const ushort* __restrict__ vtb, const float* __restrict__ isc,
                                                  ushort* __restrict__ ao){
  __shared__ ushort smem[8192];                   // 16KB: K [0,4096), V^T [4096,8192)
  const int bid = blockIdx.x;
  const int bh = bid & 31, b = bh >> 4, h = bh & 15;
  const int qt = 63 - (bid >> 5);                 // 0..63, big-first
  const int lane = threadIdx.x;
  const int la15 = lane & 15, lg = lane >> 4, l7 = lane & 7;
  const int q0w = qt * 32;

  short8 qf[2][2];
  float iscv[2];
#pragma unroll
  for (int sub = 0; sub < 2; sub++){
    int qg = q0w + sub * 16 + la15;
    size_t rb = (size_t)(b * Tc + qg) * Dc + h * DHc;
    qf[sub][0] = *(const short8*)(qb + rb + lg * 8);
    qf[sub][1] = *(const short8*)(qb + rb + 32 + lg * 8);
    iscv[sub] = isc[bh * Tc + qg];
  }

  f32x4 O[2][4];
#pragma unroll
  for (int sub = 0; sub < 2; sub++)
#pragma unroll
    for (int dt = 0; dt < 4; dt++) O[sub][dt] = f32x4{0.f, 0.f, 0.f, 0.f};
  float lacc[2] = {0.f, 0.f};

  const ushort* kbase  = kb + (size_t)b * Tc * Dc + h * DHc;
  const ushort* vtbase = vtb + (size_t)bh * DHc * Tc;
  const int ktmax = q0w + 31;

  const int Rl = lane >> 3, sl = lane & 7;
  const int gV = sl ^ (Rl & 7);

#define STAGE_KV(kt_) do { \
  _Pragma("unroll") \
  for (int i_ = 0; i_ < 8; i_++){ \
    int R_ = i_ * 8 + Rl; \
    int gk_ = sl ^ ((R_ & 3) ^ (((R_ >> 3) & 3) << 1)); \
    GLDS(kbase + (size_t)((kt_) + R_) * Dc + gk_ * 8, &smem[i_ * 512]); \
    GLDS(vtbase + (size_t)R_ * Tc + (kt_) + gV * 8, &smem[4096 + i_ * 512]); \
  } \
} while(0)

#define COMPUTE_T(kt_) do { \
  _Pragma("unroll") \
  for (int sub = 0; sub < 2; sub++){ \
    f32x4 s_[4]; \
    __builtin_amdgcn_s_setprio(1); \
    _Pragma("unroll") \
    for (int t_ = 0; t_ < 4; t_++){ \
      s_[t_] = f32x4{0.f, 0.f, 0.f, 0.f}; \
      s_[t_] = __builtin_amdgcn_mfma_f32_16x16x32_bf16(kf[t_][0], qf[sub][0], s_[t_], 0, 0, 0); \
      s_[t_] = __builtin_amdgcn_mfma_f32_16x16x32_bf16(kf[t_][1], qf[sub][1], s_[t_], 0, 0, 0); \
    } \
    __builtin_amdgcn_s_setprio(0); \
    const int qg_ = q0w + sub * 16 + la15; \
    const float sc_ = iscv[sub]; \
    const bool diag_ = ((kt_) + 63 > q0w + sub * 16); \
    uint up_[4][2]; \
    float lp_ = 0.f; \
    _Pragma("unroll") \
    for (int t_ = 0; t_ < 4; t_++){ \
      _Pragma("unroll") \
      for (int pr_ = 0; pr_ < 2; pr_++){ \
        float e0_ = exp2v(s_[t_][2 * pr_] * sc_); \
        float e1_ = exp2v(s_[t_][2 * pr_ + 1] * sc_); \
        if (diag_){ \
          int kp0_ = (kt_) + ((t_ >> 1) << 5) + lg * 8 + ((t_ & 1) << 2) + 2 * pr_; \
          if (kp0_ > qg_)     e0_ = 0.f; \
          if (kp0_ + 1 > qg_) e1_ = 0.f; \
        } \
        lp_ += e0_ + e1_; \
        up_[t_][pr_] = cvt_pk_bf16(e0_, e1_); \
      } \
    } \
    lacc[sub] += lp_; \
    __builtin_amdgcn_s_setprio(1); \
    _Pragma("unroll") \
    for (int kh_ = 0; kh_ < 2; kh_++){ \
      union { uint4v w; short8 s8; } pfr_; \
      pfr_.w[0] = up_[kh_ * 2][0];     pfr_.w[1] = up_[kh_ * 2][1]; \
      pfr_.w[2] = up_[kh_ * 2 + 1][0]; pfr_.w[3] = up_[kh_ * 2 + 1][1]; \
      _Pragma("unroll") \
      for (int dt_ = 0; dt_ < 4; dt_++) \
        O[sub][dt_] = __builtin_amdgcn_mfma_f32_16x16x32_bf16(vtf[dt_][kh_], pfr_.s8, O[sub][dt_], 0, 0, 0); \
    } \
    __builtin_amdgcn_s_setprio(0); \
  } \
} while(0)

  STAGE_KV(0);
  asm volatile("s_waitcnt vmcnt(0)" ::: "memory");
  __builtin_amdgcn_sched_barrier(0);

  for (int kt = 0;; kt += 64){
    short8 kf[4][2], vtf[4][2];
#pragma unroll
    for (int t_ = 0; t_ < 4; t_++){
      int r = ((t_ >> 1) << 5) + ((la15 >> 2) << 3) + ((t_ & 1) << 2) + (la15 & 3);
#pragma unroll
      for (int ds = 0; ds < 2; ds++){
        int g = (ds * 4 + lg) ^ ((la15 & 3) ^ ((la15 >> 2) << 1));
        kf[t_][ds] = *(const short8*)&smem[r * 64 + g * 8];
      }
    }
#pragma unroll
    for (int dt = 0; dt < 4; dt++){
      int d = dt * 16 + la15;
#pragma unroll
      for (int kh = 0; kh < 2; kh++){
        int g = (kh * 4 + lg) ^ (la15 & 7);
        vtf[dt][kh] = *(const short8*)&smem[4096 + d * 64 + g * 8];
      }
    }
    asm volatile("s_waitcnt lgkmcnt(0)" ::: "memory");
    __builtin_amdgcn_sched_barrier(0);
    STAGE_KV(kt + 64);
    COMPUTE_T(kt);
    if (kt + 64 > ktmax) break;
    asm volatile("s_waitcnt vmcnt(0)" ::: "memory");
    __builtin_amdgcn_sched_barrier(0);
  }
  asm volatile("s_waitcnt vmcnt(0)" ::: "memory");
  __builtin_amdgcn_sched_barrier(0);

  char* osb = (char*)smem;                        // 32 rows x 136 B
#pragma unroll
  for (int sub = 0; sub < 2; sub++){
    float lt = lacc[sub];
    lt += __shfl_xor(lt, 16, 64);
    lt += __shfl_xor(lt, 32, 64);
    float inv = 1.f / lt;
#pragma unroll
    for (int dt = 0; dt < 4; dt++)
#pragma unroll
      for (int pr = 0; pr < 2; pr++){
        uint u = cvt_pk_bf16(O[sub][dt][2 * pr] * inv, O[sub][dt][2 * pr + 1] * inv);
        *(uint*)(osb + (sub * 16 + la15) * 136 + (dt * 16 + lg * 4 + pr * 2) * 2) = u;
      }
  }
#pragma unroll
  for (int it = 0; it < 4; it++){
    int ql = it * 8 + (lane >> 3);
    ushort8 v = *(const ushort8*)(osb + ql * 136 + l7 * 16);
    *(ushort8*)(ao + (size_t)(b * Tc + q0w + ql) * Dc + h * DHc + l7 * 8) = v;
  }
}

// ---------------- host ----------------
extern "C" void kernel_launch(void* const* d_in, const int* in_sizes, int n_in,
                              void* d_out, int out_size, void* d_ws, size_t ws_size,
                              hipStream_t stream){
  (void)in_sizes; (void)n_in; (void)out_size; (void)ws_size;
  const float* x    = (const float*)d_in[0];
  const float* cosa = (const float*)d_in[1];
  const float* sina = (const float*)d_in[2];
  const float* sigma= (const float*)d_in[3];
  // d_in[4] = causal_mask (unused; causality handled analytically)
  const float* ln1g = (const float*)d_in[5];
  const float* ln1b = (const float*)d_in[6];
  const float* wq   = (const float*)d_in[7];
  const float* bq   = (const float*)d_in[8];
  const float* wk   = (const float*)d_in[9];
  const float* bk   = (const float*)d_in[10];
  const float* wv   = (const float*)d_in[11];
  const float* bv   = (const float*)d_in[12];
  const float* wo   = (const float*)d_in[13];
  const float* bo   = (const float*)d_in[14];
  const float* ln2g = (const float*)d_in[15];
  const float* ln2b = (const float*)d_in[16];
  const float* w1   = (const float*)d_in[17];
  const float* b1   = (const float*)d_in[18];
  const float* w2   = (const float*)d_in[19];
  const float* b2   = (const float*)d_in[20];
  float* out = (float*)d_out;

  char* ws = (char*)d_ws;
  constexpr size_t MB = 1024 * 1024;
  ushort* wqT  = (ushort*)(ws +  0 * MB);  // 2MB each; wqT/wkT/wvT contiguous = 3072x1024
  ushort* wkT  = (ushort*)(ws +  2 * MB);
  ushort* wvT  = (ushort*)(ws +  4 * MB);
  ushort* woT  = (ushort*)(ws +  6 * MB);
  ushort* w1T  = (ushort*)(ws +  8 * MB);  // 8MB  (4D x D)
  ushort* w2T  = (ushort*)(ws + 16 * MB);  // 8MB  (D x 4D)
  ushort* hb   = (ushort*)(ws + 24 * MB);  // 8MB  h (bf16); reused for h2 after attention
  ushort* qbuf = (ushort*)(ws + 32 * MB);  // 8MB; [32..64)MB reused as gelu-out (32MB) in FFN
  ushort* kbuf = (ushort*)(ws + 40 * MB);
  ushort* vtb  = (ushort*)(ws + 48 * MB);  // 8MB  V^T [bh][64 d][2048 t]
  ushort* aob  = (ushort*)(ws + 56 * MB);
  float*  x2   = (float*)(ws + 64 * MB);   // 16MB
  float*  iscp = (float*)(ws + 80 * MB);   // 256KB
  ushort* g1b  = qbuf;                     // 32MB alias over qbuf/kbuf/vtb/aob (dead by then)

  // 1. ALL weight transposes in one launch
  k_transcvt_all<<<12288, 256, 0, stream>>>(wq, wk, wv, wo, w1, w2, wqT, wkT, wvT, woT, w1T, w2T);
  // 2. LN1
  k_ln<<<Rc, 256, 0, stream>>>(x, ln1g, ln1b, hb);
  // 3. fused QKV projection + RoPE epilogue (n64 tile -> 3 blocks/CU)
  k_gemm_qkv64<<<dim3(3 * Dc / 64, Rc / 128), 256, 0, stream>>>(hb, wqT, bq, bk, bv, qbuf, kbuf, vtb,
                                                                cosa, sina, Dc);
  // 4. temperature -> inv scale (exp2 domain)
  k_iscale<<<(Bc * Tc * Hc) / 256, 256, 0, stream>>>(sigma, iscp);
  // 5. causal attention (MFMA flash, single-buffer GLDS-pipelined)
  k_attn_mfma<<<dim3(2048), 64, 0, stream>>>(qbuf, kbuf, vtb, iscp, aob);
  // 6. out-proj + residual (f32 out, n64 tile)
  k_gemm_n64<<<dim3(Dc / 64, Rc / 128), 256, 0, stream>>>(aob, woT, bo, x, x2, Rc, Dc, Dc);
  // 7. LN2
  k_ln<<<Rc, 256, 0, stream>>>(x2, ln2g, ln2b, hb);
  // 8. FFN1 + exact GELU (bf16 out, n64 tile)
  k_gemm_n64b<<<dim3(D4c / 64, Rc / 128), 256, 0, stream>>>(hb, w1T, b1, g1b, Rc, D4c, Dc);
  // 9. FFN2 + residual -> final output (f32, n64 tile)
  k_gemm_n64<<<dim3(Dc / 64, Rc / 128), 256, 0, stream>>>(g1b, w2T, b2, x2, out, Rc, Dc, D4c);
}

// Round 20
// 220.590 us; speedup vs baseline: 1.0429x; 1.0241x over previous
//
#include <hip/hip_runtime.h>

typedef unsigned short ushort;
typedef unsigned int uint;

typedef __attribute__((ext_vector_type(8))) short short8;     // bf16x8 MFMA frag
typedef __attribute__((ext_vector_type(8))) unsigned short ushort8;
typedef __attribute__((ext_vector_type(4))) unsigned short ushort4v;
typedef __attribute__((ext_vector_type(4))) float f32x4;
typedef __attribute__((ext_vector_type(4))) uint uint4v;

#define DEV static __device__ __forceinline__

DEV ushort f2b(float f){
  union { float f; uint u; } v; v.f = f;
  uint u = v.u;
  u += 0x7fffu + ((u >> 16) & 1u);   // round-to-nearest-even
  return (ushort)(u >> 16);
}
DEV float b2f(ushort h){
  union { uint u; float f; } v; v.u = ((uint)h) << 16;
  return v.f;
}
DEV uint cvt_pk_bf16(float lo, float hi){   // {bf16(lo), bf16(hi)} packed, RNE
  uint r;
  asm("v_cvt_pk_bf16_f32 %0, %1, %2" : "=v"(r) : "v"(lo), "v"(hi));
  return r;
}
DEV ushort f2b1(float f){ return (ushort)cvt_pk_bf16(f, f); }  // 1-inst bf16 convert
DEV float exp2v(float x){                   // 2^x, 1 inst
  float r;
  asm("v_exp_f32 %0, %1" : "=v"(r) : "v"(x));
  return r;
}
// exact-GELU via A&S 7.1.26 erf (|err| < 1.5e-7), exp2/rcp based
DEV float gelu_f(float x){
  float z = fabsf(x) * 0.70710678118654752f;
  float t = __builtin_amdgcn_rcpf(1.f + 0.3275911f * z);
  float poly = t * (0.254829592f + t * (-0.284496736f + t * (1.421413741f +
               t * (-1.453152027f + t * 1.061405429f))));
  float e = exp2v(-z * z * 1.44269504088896f);
  float erf_abs = 1.f - poly * e;
  float erf_s = copysignf(erf_abs, x);
  return 0.5f * x * (1.f + erf_s);
}

constexpr int Bc = 2, Tc = 2048, Dc = 1024, Hc = 16, DHc = 64, NBc = 32;
constexpr int Rc = Bc * Tc;   // 4096 rows
constexpr int D4c = 4 * Dc;   // 4096

// ---------------- ALL weight transposes + f32->bf16 in ONE launch ----------------
__global__ __launch_bounds__(256) void k_transcvt_all(
    const float* __restrict__ wq, const float* __restrict__ wk, const float* __restrict__ wv,
    const float* __restrict__ wo, const float* __restrict__ w1, const float* __restrict__ w2,
    ushort* __restrict__ wqT, ushort* __restrict__ wkT, ushort* __restrict__ wvT,
    ushort* __restrict__ woT, ushort* __restrict__ w1T, ushort* __restrict__ w2T){
  __shared__ float tile[32][33];
  const int bid = blockIdx.x;
  const float* in; ushort* out; int K, N, bx, by;
  if (bid < 4096){
    int seg = bid >> 10, loc = bid & 1023;
    in  = seg == 0 ? wq  : seg == 1 ? wk  : seg == 2 ? wv  : wo;
    out = seg == 0 ? wqT : seg == 1 ? wkT : seg == 2 ? wvT : woT;
    K = 1024; N = 1024; bx = loc & 31; by = loc >> 5;
  } else if (bid < 8192){
    int loc = bid - 4096;
    in = w1; out = w1T; K = 1024; N = 4096; bx = loc & 127; by = loc >> 7;
  } else {
    int loc = bid - 8192;
    in = w2; out = w2T; K = 4096; N = 1024; bx = loc & 31; by = loc >> 5;
  }
  int n0 = bx * 32, k0 = by * 32;
  int c = threadIdx.x & 31, r0 = threadIdx.x >> 5;
#pragma unroll
  for (int i = 0; i < 4; i++){
    int k = r0 + i * 8;
    tile[k][c] = in[(size_t)(k0 + k) * N + n0 + c];
  }
  __syncthreads();
#pragma unroll
  for (int i = 0; i < 4; i++){
    int n = r0 + i * 8;
    out[(size_t)(n0 + n) * K + k0 + c] = f2b(tile[c][n]);
  }
}

// ---------------- LayerNorm: f32 (R,D) -> bf16 (R,D) ----------------
__global__ __launch_bounds__(256) void k_ln(const float* __restrict__ x, const float* __restrict__ g,
                                            const float* __restrict__ bb, ushort* __restrict__ out){
  int row = blockIdx.x, tid = threadIdx.x;
  const f32x4* xr = (const f32x4*)(x + (size_t)row * Dc);
  f32x4 v = xr[tid];
  float s  = v.x + v.y + v.z + v.w;
  float ss = v.x*v.x + v.y*v.y + v.z*v.z + v.w*v.w;
#pragma unroll
  for (int off = 32; off > 0; off >>= 1){
    s  += __shfl_xor(s,  off, 64);
    ss += __shfl_xor(ss, off, 64);
  }
  __shared__ float red[2][4];
  int w = tid >> 6;
  if ((tid & 63) == 0){ red[0][w] = s; red[1][w] = ss; }
  __syncthreads();
  s  = red[0][0] + red[0][1] + red[0][2] + red[0][3];
  ss = red[1][0] + red[1][1] + red[1][2] + red[1][3];
  float mu  = s * (1.f / Dc);
  float var = ss * (1.f / Dc) - mu * mu;
  float rs  = rsqrtf(var + 1e-5f);
  f32x4 gv = ((const f32x4*)g)[tid];
  f32x4 bv = ((const f32x4*)bb)[tid];
  ushort4v o;
  o.x = f2b((v.x - mu) * rs * gv.x + bv.x);
  o.y = f2b((v.y - mu) * rs * gv.y + bv.y);
  o.z = f2b((v.z - mu) * rs * gv.z + bv.z);
  o.w = f2b((v.w - mu) * rs * gv.w + bv.w);
  ((ushort4v*)(out + (size_t)row * Dc))[tid] = o;
}

#define GLDS(src, dst) __builtin_amdgcn_global_load_lds( \
    (const __attribute__((address_space(1))) void*)(src), \
    (__attribute__((address_space(3))) void*)(dst), 16, 0, 0)

// ---------------- 128x64 bf16 MFMA GEMM staging/core (shared by n64 variants) ----------------
#define STAGE64(nb_, k0_) do { \
  _Pragma("unroll") \
  for (int i_ = 0; i_ < 4; i_++){ \
    int chunk_ = w * 4 + i_; \
    GLDS(A + (size_t)(m0 + chunk_ * 8 + rloc) * K + (k0_) + gsrc * 8, &SM[nb_][chunk_ * 512]); \
  } \
  _Pragma("unroll") \
  for (int j_ = 0; j_ < 2; j_++){ \
    int chunk_ = w * 2 + j_; \
    GLDS(Bt + (size_t)(n0 + chunk_ * 8 + rloc) * K + (k0_) + gsrc * 8, &SM[nb_][8192 + chunk_ * 512]); \
  } \
} while(0)

#define CORE64(cb_) do { \
  _Pragma("unroll") \
  for (int ks = 0; ks < 2; ks++){ \
    const int gs = (ks * 4 + lg) ^ l7; \
    short8 aF[2], bF[4]; \
    _Pragma("unroll") \
    for (int mi = 0; mi < 2; mi++) aF[mi] = *(const short8*)&SM[cb_][(arow + mi * 16) * 64 + gs * 8]; \
    _Pragma("unroll") \
    for (int ni = 0; ni < 4; ni++) bF[ni] = *(const short8*)&SM[cb_][8192 + (ni * 16 + la15) * 64 + gs * 8]; \
    _Pragma("unroll") \
    for (int mi = 0; mi < 2; mi++) \
      _Pragma("unroll") \
      for (int ni = 0; ni < 4; ni++) \
        acc[mi][ni] = __builtin_amdgcn_mfma_f32_16x16x32_bf16(aF[mi], bF[ni], acc[mi][ni], 0, 0, 0); \
  } \
} while(0)

#define N64_LOOP() do { \
  STAGE64(0, 0); \
  __syncthreads(); \
  const int NT_ = K >> 6; \
  for (int t = 0; t < NT_; t++){ \
    const int cb = t & 1; \
    if (t + 1 < NT_) STAGE64(cb ^ 1, (t + 1) << 6); \
    CORE64(cb); \
    __syncthreads(); \
  } \
} while(0)

// ---------------- n64, f32 out + residual (FFN2 / out-proj): 48KB LDS -> 3 blocks/CU ----------------
__global__ __launch_bounds__(256) void k_gemm_n64(const ushort* __restrict__ A, const ushort* __restrict__ Bt,
                                                  const float* __restrict__ bias, const float* __restrict__ resid,
                                                  float* __restrict__ Cout, int M, int N, int K){
  __shared__ ushort SM[2][12288];                 // [buf]: A [0,8192), B [8192,12288)
  const int tid = threadIdx.x;
  const int m0 = blockIdx.y * 128, n0 = blockIdx.x * 64;
  const int w = tid >> 6, lane = tid & 63;
  const int la15 = lane & 15, lg = lane >> 4, l7 = lane & 7;
  const int rloc = lane >> 3, gsrc = (lane & 7) ^ rloc;

  f32x4 acc[2][4];
#pragma unroll
  for (int i = 0; i < 2; i++)
#pragma unroll
    for (int j = 0; j < 4; j++) acc[i][j] = f32x4{0.f, 0.f, 0.f, 0.f};

  const int arow = w * 32 + la15;

  N64_LOOP();

#pragma unroll
  for (int mi = 0; mi < 2; mi++)
#pragma unroll
    for (int ni = 0; ni < 4; ni++){
      int cc = n0 + ni * 16 + la15;
      float bv = bias[cc];
      f32x4 a4 = acc[mi][ni];
#pragma unroll
      for (int r = 0; r < 4; r++){
        int rr = m0 + w * 32 + mi * 16 + lg * 4 + r;
        float v = a4[r] + bv + resid[(size_t)rr * N + cc];
        Cout[(size_t)rr * N + cc] = v;
      }
    }
}

// ---------------- n64, bf16 out + GELU (FFN1): 48KB LDS -> 3 blocks/CU ----------------
__global__ __launch_bounds__(256) void k_gemm_n64b(const ushort* __restrict__ A, const ushort* __restrict__ Bt,
                                                   const float* __restrict__ bias,
                                                   ushort* __restrict__ Cout, int M, int N, int K){
  __shared__ ushort SM[2][12288];
  const int tid = threadIdx.x;
  const int m0 = blockIdx.y * 128, n0 = blockIdx.x * 64;
  const int w = tid >> 6, lane = tid & 63;
  const int la15 = lane & 15, lg = lane >> 4, l7 = lane & 7;
  const int rloc = lane >> 3, gsrc = (lane & 7) ^ rloc;

  f32x4 acc[2][4];
#pragma unroll
  for (int i = 0; i < 2; i++)
#pragma unroll
    for (int j = 0; j < 4; j++) acc[i][j] = f32x4{0.f, 0.f, 0.f, 0.f};

  const int arow = w * 32 + la15;

  N64_LOOP();

  // epilogue: gelu -> bf16 through LDS bounce Cs[128][72]
  ushort* Cs = &SM[0][0];
#pragma unroll
  for (int mi = 0; mi < 2; mi++)
#pragma unroll
    for (int ni = 0; ni < 4; ni++){
      int ccl = ni * 16 + la15;
      float bv = bias[n0 + ccl];
      f32x4 a4 = acc[mi][ni];
#pragma unroll
      for (int r = 0; r < 4; r++){
        int rl = w * 32 + mi * 16 + lg * 4 + r;
        Cs[rl * 72 + ccl] = f2b1(gelu_f(a4[r] + bv));
      }
    }
  __syncthreads();
#pragma unroll
  for (int p = 0; p < 4; p++){
    int row = p * 32 + (tid >> 3);
    int col = (tid & 7) * 8;
    ushort8 vv = *(const ushort8*)&Cs[row * 72 + col];
    *(ushort8*)(Cout + (size_t)(m0 + row) * N + n0 + col) = vv;
  }
}

// ---------------- n64 fused QKV GEMM + RoPE epilogue; V written transposed vT[bh][d][t] ----------------
__global__ __launch_bounds__(256) void k_gemm_qkv64(const ushort* __restrict__ A, const ushort* __restrict__ Bt,
                                                    const float* __restrict__ bq_, const float* __restrict__ bk_,
                                                    const float* __restrict__ bv_, ushort* __restrict__ oq,
                                                    ushort* __restrict__ ok, ushort* __restrict__ ovt,
                                                    const float* __restrict__ cosa, const float* __restrict__ sina,
                                                    int K){
  __shared__ ushort SM[2][12288];
  const int tid = threadIdx.x;
  const int m0 = blockIdx.y * 128, n0 = blockIdx.x * 64;
  const int w = tid >> 6, lane = tid & 63;
  const int la15 = lane & 15, lg = lane >> 4, l7 = lane & 7;
  const int rloc = lane >> 3, gsrc = (lane & 7) ^ rloc;

  f32x4 acc[2][4];
#pragma unroll
  for (int i = 0; i < 2; i++)
#pragma unroll
    for (int j = 0; j < 4; j++) acc[i][j] = f32x4{0.f, 0.f, 0.f, 0.f};

  const int arow = w * 32 + la15;

  N64_LOOP();

  const int sel = n0 >> 10;                       // 0=Q, 1=K, 2=V (uniform per block)
  ushort* Cs = &SM[0][0];
  if (sel < 2){
    const float* bias = sel == 0 ? bq_ : bk_;
    ushort* o = sel == 0 ? oq : ok;
#pragma unroll
    for (int mi = 0; mi < 2; mi++)
#pragma unroll
      for (int ni = 0; ni < 4; ni++){
        int ccl = ni * 16 + la15;
        float bv = bias[(n0 & 1023) + ccl];
        f32x4 a4 = acc[mi][ni];
#pragma unroll
        for (int r = 0; r < 4; r++){
          int rl = w * 32 + mi * 16 + lg * 4 + r;
          Cs[rl * 72 + ccl] = f2b1(a4[r] + bv);
        }
      }
    __syncthreads();
#pragma unroll
    for (int p = 0; p < 4; p++){
      int row = p * 32 + (tid >> 3);
      int col = (tid & 7) * 8;
      ushort8 vv = *(const ushort8*)&Cs[row * 72 + col];
      int rr = m0 + row;
      int bb2 = rr >> 11, tt2 = rr & 2047;
      int cg = (n0 & 1023) + col;
      int hh2 = cg >> 6;
      int nb0 = (cg & 63) >> 1;
      size_t ai = ((size_t)(bb2 * Hc + hh2) * Tc + tt2) * NBc + nb0;
      f32x4 cv = *(const f32x4*)(cosa + ai);
      f32x4 sv = *(const f32x4*)(sina + ai);
      ushort8 ov;
#pragma unroll
      for (int j2 = 0; j2 < 4; j2++){
        float x1 = b2f((ushort)vv[2 * j2]), x2 = b2f((ushort)vv[2 * j2 + 1]);
        uint pk = cvt_pk_bf16(x1 * cv[j2] - x2 * sv[j2], x1 * sv[j2] + x2 * cv[j2]);
        ov[2 * j2]     = (ushort)(pk & 0xffff);
        ov[2 * j2 + 1] = (ushort)(pk >> 16);
      }
      *(ushort8*)(o + (size_t)rr * Dc + cg) = ov;
    }
  } else {
    // V: transpose bounce Cs[nloc 64][tloc 136], 16B stores along t (no rope)
#pragma unroll
    for (int mi = 0; mi < 2; mi++)
#pragma unroll
      for (int ni = 0; ni < 4; ni++){
        int ccl = ni * 16 + la15;                 // nloc 0..63
        float bv = bv_[(n0 - 2048) + ccl];
        f32x4 a4 = acc[mi][ni];
#pragma unroll
        for (int r = 0; r < 4; r++){
          int rl = w * 32 + mi * 16 + lg * 4 + r; // tloc 0..127
          Cs[ccl * 136 + rl] = f2b1(a4[r] + bv);
        }
      }
    __syncthreads();
    const int bb = m0 >> 11, t0 = m0 & 2047;
#pragma unroll
    for (int p = 0; p < 4; p++){
      int nl = p * 16 + (tid >> 4);               // 0..63
      int tl = (tid & 15) * 8;                    // 0..120
      ushort8 vv = *(const ushort8*)&Cs[nl * 136 + tl];
      int ng = (n0 - 2048) + nl;                  // hh*64 + d
      *(ushort8*)(ovt + ((size_t)(bb * 1024 + ng) << 11) + t0 + tl) = vv;
    }
  }
}

// ---------------- inv scale (exp2 domain): log2e / (8 * (1 + mean_nb sigma)), (B,H,T) ----------------
__global__ __launch_bounds__(256) void k_iscale(const float* __restrict__ sigma, float* __restrict__ isc){
  int idx = blockIdx.x * 256 + threadIdx.x;       // B*T*H = 65536, idx = (b*T+t)*H + h
  int hh = idx & 15;
  int t  = (idx >> 4) & 2047;
  int b  = idx >> 15;
  const f32x4* sp = (const f32x4*)(sigma + (size_t)idx * NBc);
  float s = 0.f;
#pragma unroll
  for (int i = 0; i < 8; i++){ f32x4 v = sp[i]; s += v.x + v.y + v.z + v.w; }
  isc[(b * Hc + hh) * Tc + t] = 1.44269504088896f / (8.f * (1.f + s * (1.f / NBc)));
}

// ---------------- MFMA causal flash attention: 2-wave blocks, shared K/V staging ----------------
// Grid 1024 x 128 threads (2 waves). Each block owns 64 q-rows (wave w: q0+w*32..+31).
// Wave 0 stages K (8 GLDS), wave 1 stages V^T (8 GLDS) -> HALF the per-row L2 traffic vs
// 1-wave blocks. 16KB LDS; blocks/CU=4 -> 8 waves/CU (same TLP as before). Per iter:
// ds_read frags -> lgkmcnt(0) -> sync (all reads done) -> STAGE(kt+64) -> compute(kt,
// guarded) -> sync (barrier drains vmcnt -> staging visible to both waves).
// Zero-shuffle permuted-K compute; fixed m=0 softmax; deferred l reduction (round-7 proven).
__global__ __launch_bounds__(128) void k_attn_mfma(const ushort* __restrict__ qb, const ushort* __restrict__ kb,
                                                   const ushort* __restrict__ vtb, const float* __restrict__ isc,
                                                   ushort* __restrict__ ao){
  __shared__ ushort smem[8192];                   // 16KB: K [0,4096), V^T [4096,8192)
  const int bid = blockIdx.x;
  const int bh = bid & 31, b = bh >> 4, h = bh & 15;
  const int qt = 31 - (bid >> 5);                 // 0..31, big-first
  const int tid = threadIdx.x;
  const int wq = tid >> 6, lane = tid & 63;
  const int la15 = lane & 15, lg = lane >> 4, l7 = lane & 7;
  const int q0 = qt * 64;
  const int q0w = q0 + wq * 32;

  short8 qf[2][2];
  float iscv[2];
#pragma unroll
  for (int sub = 0; sub < 2; sub++){
    int qg = q0w + sub * 16 + la15;
    size_t rb = (size_t)(b * Tc + qg) * Dc + h * DHc;
    qf[sub][0] = *(const short8*)(qb + rb + lg * 8);
    qf[sub][1] = *(const short8*)(qb + rb + 32 + lg * 8);
    iscv[sub] = isc[bh * Tc + qg];
  }

  f32x4 O[2][4];
#pragma unroll
  for (int sub = 0; sub < 2; sub++)
#pragma unroll
    for (int dt = 0; dt < 4; dt++) O[sub][dt] = f32x4{0.f, 0.f, 0.f, 0.f};
  float lacc[2] = {0.f, 0.f};

  const ushort* kbase  = kb + (size_t)b * Tc * Dc + h * DHc;
  const ushort* vtbase = vtb + (size_t)bh * DHc * Tc;

  const int Rl = lane >> 3, sl = lane & 7;
  const int gV = sl ^ (Rl & 7);

  // wave 0 stages K rows, wave 1 stages V^T rows (uniform per wave, overread-safe)
#define STAGE_KV(kt_) do { \
  if (wq == 0){ \
    _Pragma("unroll") \
    for (int i_ = 0; i_ < 8; i_++){ \
      int R_ = i_ * 8 + Rl; \
      int gk_ = sl ^ ((R_ & 3) ^ (((R_ >> 3) & 3) << 1)); \
      GLDS(kbase + (size_t)((kt_) + R_) * Dc + gk_ * 8, &smem[i_ * 512]); \
    } \
  } else { \
    _Pragma("unroll") \
    for (int i_ = 0; i_ < 8; i_++){ \
      int R_ = i_ * 8 + Rl; \
      GLDS(vtbase + (size_t)R_ * Tc + (kt_) + gV * 8, &smem[4096 + i_ * 512]); \
    } \
  } \
} while(0)

#define COMPUTE_T(kt_) do { \
  _Pragma("unroll") \
  for (int sub = 0; sub < 2; sub++){ \
    f32x4 s_[4]; \
    __builtin_amdgcn_s_setprio(1); \
    _Pragma("unroll") \
    for (int t_ = 0; t_ < 4; t_++){ \
      s_[t_] = f32x4{0.f, 0.f, 0.f, 0.f}; \
      s_[t_] = __builtin_amdgcn_mfma_f32_16x16x32_bf16(kf[t_][0], qf[sub][0], s_[t_], 0, 0, 0); \
      s_[t_] = __builtin_amdgcn_mfma_f32_16x16x32_bf16(kf[t_][1], qf[sub][1], s_[t_], 0, 0, 0); \
    } \
    __builtin_amdgcn_s_setprio(0); \
    const int qg_ = q0w + sub * 16 + la15; \
    const float sc_ = iscv[sub]; \
    const bool diag_ = ((kt_) + 63 > q0w + sub * 16); \
    uint up_[4][2]; \
    float lp_ = 0.f; \
    _Pragma("unroll") \
    for (int t_ = 0; t_ < 4; t_++){ \
      _Pragma("unroll") \
      for (int pr_ = 0; pr_ < 2; pr_++){ \
        float e0_ = exp2v(s_[t_][2 * pr_] * sc_); \
        float e1_ = exp2v(s_[t_][2 * pr_ + 1] * sc_); \
        if (diag_){ \
          int kp0_ = (kt_) + ((t_ >> 1) << 5) + lg * 8 + ((t_ & 1) << 2) + 2 * pr_; \
          if (kp0_ > qg_)     e0_ = 0.f; \
          if (kp0_ + 1 > qg_) e1_ = 0.f; \
        } \
        lp_ += e0_ + e1_; \
        up_[t_][pr_] = cvt_pk_bf16(e0_, e1_); \
      } \
    } \
    lacc[sub] += lp_; \
    __builtin_amdgcn_s_setprio(1); \
    _Pragma("unroll") \
    for (int kh_ = 0; kh_ < 2; kh_++){ \
      union { uint4v w; short8 s8; } pfr_; \
      pfr_.w[0] = up_[kh_ * 2][0];     pfr_.w[1] = up_[kh_ * 2][1]; \
      pfr_.w[2] = up_[kh_ * 2 + 1][0]; pfr_.w[3] = up_[kh_ * 2 + 1][1]; \
      _Pragma("unroll") \
      for (int dt_ = 0; dt_ < 4; dt_++) \
        O[sub][dt_] = __builtin_amdgcn_mfma_f32_16x16x32_bf16(vtf[dt_][kh_], pfr_.s8, O[sub][dt_], 0, 0, 0); \
    } \
    __builtin_amdgcn_s_setprio(0); \
  } \
} while(0)

  STAGE_KV(0);
  __syncthreads();                                // prologue staging drained (barrier drains vmcnt)

  const int ktend = q0 + 63;
  for (int kt = 0;; kt += 64){
    short8 kf[4][2], vtf[4][2];
#pragma unroll
    for (int t_ = 0; t_ < 4; t_++){
      int r = ((t_ >> 1) << 5) + ((la15 >> 2) << 3) + ((t_ & 1) << 2) + (la15 & 3);
#pragma unroll
      for (int ds = 0; ds < 2; ds++){
        int g = (ds * 4 + lg) ^ ((la15 & 3) ^ ((la15 >> 2) << 1));
        kf[t_][ds] = *(const short8*)&smem[r * 64 + g * 8];
      }
    }
#pragma unroll
    for (int dt = 0; dt < 4; dt++){
      int d = dt * 16 + la15;
#pragma unroll
      for (int kh = 0; kh < 2; kh++){
        int g = (kh * 4 + lg) ^ (la15 & 7);
        vtf[dt][kh] = *(const short8*)&smem[4096 + d * 64 + g * 8];
      }
    }
    asm volatile("s_waitcnt lgkmcnt(0)" ::: "memory");
    __builtin_amdgcn_sched_barrier(0);
    __syncthreads();                              // both waves' reads complete
    STAGE_KV(kt + 64);                            // prefetch next tile (overread-safe)
    if (kt <= q0w + 31) COMPUTE_T(kt);            // wave-uniform guard
    if (kt + 64 > ktend) break;
    __syncthreads();                              // staging drained + compute done
  }
  __syncthreads();                                // drain trailing prefetch before epilogue overlay

  // epilogue: per-wave region of smem (2 x 4352 B), reduce l once, normalize, coalesced store
  char* osb = (char*)smem + wq * 4352;            // 32 rows x 136 B per wave
#pragma unroll
  for (int sub = 0; sub < 2; sub++){
    float lt = lacc[sub];
    lt += __shfl_xor(lt, 16, 64);
    lt += __shfl_xor(lt, 32, 64);
    float inv = 1.f / lt;
#pragma unroll
    for (int dt = 0; dt < 4; dt++)
#pragma unroll
      for (int pr = 0; pr < 2; pr++){
        uint u = cvt_pk_bf16(O[sub][dt][2 * pr] * inv, O[sub][dt][2 * pr + 1] * inv);
        *(uint*)(osb + (sub * 16 + la15) * 136 + (dt * 16 + lg * 4 + pr * 2) * 2) = u;
      }
  }
#pragma unroll
  for (int it = 0; it < 4; it++){
    int ql = it * 8 + (lane >> 3);
    ushort8 v = *(const ushort8*)(osb + ql * 136 + l7 * 16);
    *(ushort8*)(ao + (size_t)(b * Tc + q0w + ql) * Dc + h * DHc + l7 * 8) = v;
  }
}

// ---------------- host ----------------
extern "C" void kernel_launch(void* const* d_in, const int* in_sizes, int n_in,
                              void* d_out, int out_size, void* d_ws, size_t ws_size,
                              hipStream_t stream){
  (void)in_sizes; (void)n_in; (void)out_size; (void)ws_size;
  const float* x    = (const float*)d_in[0];
  const float* cosa = (const float*)d_in[1];
  const float* sina = (const float*)d_in[2];
  const float* sigma= (const float*)d_in[3];
  // d_in[4] = causal_mask (unused; causality handled analytically)
  const float* ln1g = (const float*)d_in[5];
  const float* ln1b = (const float*)d_in[6];
  const float* wq   = (const float*)d_in[7];
  const float* bq   = (const float*)d_in[8];
  const float* wk   = (const float*)d_in[9];
  const float* bk   = (const float*)d_in[10];
  const float* wv   = (const float*)d_in[11];
  const float* bv   = (const float*)d_in[12];
  const float* wo   = (const float*)d_in[13];
  const float* bo   = (const float*)d_in[14];
  const float* ln2g = (const float*)d_in[15];
  const float* ln2b = (const float*)d_in[16];
  const float* w1   = (const float*)d_in[17];
  const float* b1   = (const float*)d_in[18];
  const float* w2   = (const float*)d_in[19];
  const float* b2   = (const float*)d_in[20];
  float* out = (float*)d_out;

  char* ws = (char*)d_ws;
  constexpr size_t MB = 1024 * 1024;
  ushort* wqT  = (ushort*)(ws +  0 * MB);  // 2MB each; wqT/wkT/wvT contiguous = 3072x1024
  ushort* wkT  = (ushort*)(ws +  2 * MB);
  ushort* wvT  = (ushort*)(ws +  4 * MB);
  ushort* woT  = (ushort*)(ws +  6 * MB);
  ushort* w1T  = (ushort*)(ws +  8 * MB);  // 8MB  (4D x D)
  ushort* w2T  = (ushort*)(ws + 16 * MB);  // 8MB  (D x 4D)
  ushort* hb   = (ushort*)(ws + 24 * MB);  // 8MB  h (bf16); reused for h2 after attention
  ushort* qbuf = (ushort*)(ws + 32 * MB);  // 8MB; [32..64)MB reused as gelu-out (32MB) in FFN
  ushort* kbuf = (ushort*)(ws + 40 * MB);
  ushort* vtb  = (ushort*)(ws + 48 * MB);  // 8MB  V^T [bh][64 d][2048 t]
  ushort* aob  = (ushort*)(ws + 56 * MB);
  float*  x2   = (float*)(ws + 64 * MB);   // 16MB
  float*  iscp = (float*)(ws + 80 * MB);   // 256KB
  ushort* g1b  = qbuf;                     // 32MB alias over qbuf/kbuf/vtb/aob (dead by then)

  // 1. ALL weight transposes in one launch
  k_transcvt_all<<<12288, 256, 0, stream>>>(wq, wk, wv, wo, w1, w2, wqT, wkT, wvT, woT, w1T, w2T);
  // 2. LN1
  k_ln<<<Rc, 256, 0, stream>>>(x, ln1g, ln1b, hb);
  // 3. fused QKV projection + RoPE epilogue (n64 tile -> 3 blocks/CU)
  k_gemm_qkv64<<<dim3(3 * Dc / 64, Rc / 128), 256, 0, stream>>>(hb, wqT, bq, bk, bv, qbuf, kbuf, vtb,
                                                                cosa, sina, Dc);
  // 4. temperature -> inv scale (exp2 domain)
  k_iscale<<<(Bc * Tc * Hc) / 256, 256, 0, stream>>>(sigma, iscp);
  // 5. causal attention (MFMA flash, 2-wave shared-staging)
  k_attn_mfma<<<dim3(1024), 128, 0, stream>>>(qbuf, kbuf, vtb, iscp, aob);
  // 6. out-proj + residual (f32 out, n64 tile)
  k_gemm_n64<<<dim3(Dc / 64, Rc / 128), 256, 0, stream>>>(aob, woT, bo, x, x2, Rc, Dc, Dc);
  // 7. LN2
  k_ln<<<Rc, 256, 0, stream>>>(x2, ln2g, ln2b, hb);
  // 8. FFN1 + exact GELU (bf16 out, n64 tile)
  k_gemm_n64b<<<dim3(D4c / 64, Rc / 128), 256, 0, stream>>>(hb, w1T, b1, g1b, Rc, D4c, Dc);
  // 9. FFN2 + residual -> final output (f32, n64 tile)
  k_gemm_n64<<<dim3(Dc / 64, Rc / 128), 256, 0, stream>>>(g1b, w2T, b2, x2, out, Rc, Dc, D4c);
}